// Round 11
// baseline (156.720 us; speedup 1.0000x reference)
//
#include <hip/hip_runtime.h>

#define NNODES 50000
#define EEDGES 800000
#define FIN 128
#define FH 128
#define FOUT 16
#define BN_EPS 1e-5f
#define NBIN 391      // ceil(50000/128) bins of 128 dst nodes
#define CAP 4096      // fixed edge capacity per bin (expected ~2048, max ~2250)
#define PCH 8192      // edges per partition block
#define NPB 98        // ceil(800000/8192)
#define NTILES 1563   // ceil(50000/32) lin1 row tiles
#define PACKBLKS 3143 // 6,436,864 elems / (256*8)

typedef short bf16x8 __attribute__((ext_vector_type(8)));
typedef float f32x4 __attribute__((ext_vector_type(4)));

__device__ inline unsigned short tobf16(float f) {
    unsigned int u = __float_as_uint(f);
    u += 0x7fffu + ((u >> 16) & 1u);   // RNE
    return (unsigned short)(u >> 16);
}
__device__ inline float frombf16(unsigned short h) {
    return __uint_as_float(((unsigned int)h) << 16);
}
__device__ inline unsigned packbf(float f0, float f1) {
    return (unsigned)tobf16(f0) | ((unsigned)tobf16(f1) << 16);
}
__device__ inline float lo16(unsigned u) { return __uint_as_float(u << 16); }
__device__ inline float hi16(unsigned u) { return __uint_as_float(u & 0xffff0000u); }

// ---------------- K1: partition (blocks 0..97) || pack (blocks 98..) ----------------
__global__ void part_pack_kernel(const int* __restrict__ src, const int* __restrict__ dst,
                                 int* __restrict__ binFill, unsigned int* __restrict__ edgeBin,
                                 const float* __restrict__ x,
                                 const float* __restrict__ Wl1, const float* __restrict__ Wr1,
                                 const float* __restrict__ Wl2, const float* __restrict__ Wr2,
                                 unsigned short* __restrict__ xb, unsigned short* __restrict__ wb) {
    __shared__ int hist[NBIN];
    __shared__ int runBase[NBIN];
    __shared__ int runFill[NBIN];
    int t = threadIdx.x;
    if (blockIdx.x < NPB) {
        // ---- partition path ----
        for (int i = t; i < NBIN; i += 256) { hist[i] = 0; runFill[i] = 0; }
        __syncthreads();
        int e0 = blockIdx.x * PCH;
        for (int i = 0; i < PCH / 256; ++i) {
            int e = e0 + i * 256 + t;
            if (e < EEDGES) atomicAdd(&hist[dst[e] >> 7], 1);
        }
        __syncthreads();
        for (int i = t; i < NBIN; i += 256) {
            int c = hist[i];
            if (c) runBase[i] = atomicAdd(&binFill[i], c);
        }
        __syncthreads();
        for (int i = 0; i < PCH / 256; ++i) {
            int e = e0 + i * 256 + t;
            if (e < EEDGES) {
                int d = dst[e];
                int b = d >> 7;
                int off = runBase[b] + atomicAdd(&runFill[b], 1);
                if (off < CAP)
                    edgeBin[(size_t)b * CAP + off] = ((unsigned)(d & 127) << 17) | (unsigned)src[e];
            }
        }
    } else {
        // ---- pack path: 8 elems/thread ----
        int tt = (blockIdx.x - NPB) * 256 + t;
        int base = tt * 8;
        const float* srcp;
        unsigned short* dstp;
        int off;
        if (base < NNODES * FIN) {
            srcp = x; off = base; dstp = xb + base;
        } else {
            int w = base - NNODES * FIN;
            if (w >= 36864) return;
            dstp = wb + w;
            if (w < 16384)      { srcp = Wl1; off = w; }
            else if (w < 32768) { srcp = Wr1; off = w - 16384; }
            else if (w < 34816) { srcp = Wl2; off = w - 32768; }
            else                { srcp = Wr2; off = w - 34816; }
        }
        float4 f0 = *reinterpret_cast<const float4*>(srcp + off);
        float4 f1 = *reinterpret_cast<const float4*>(srcp + off + 4);
        uint4 r;
        r.x = packbf(f0.x, f0.y);
        r.y = packbf(f0.z, f0.w);
        r.z = packbf(f1.x, f1.y);
        r.w = packbf(f1.z, f1.w);
        *reinterpret_cast<uint4*>(dstp) = r;
    }
}

// ---------------- K2: fused bucket: binOff reduction + LDS histogram/scan + scatter --------
__global__ void bucket_fused_kernel(const unsigned int* __restrict__ edgeBin,
                                    const int* __restrict__ binFill,
                                    int* __restrict__ srcSorted,
                                    int* __restrict__ rowstart) {
    __shared__ unsigned eb[CAP];     // 16 KB staging of this bin's edges
    __shared__ int cnt[128];
    __shared__ int sc[128];
    __shared__ int wp[128];
    __shared__ int wsum[4];
    int b = blockIdx.x;
    int t = threadIdx.x;

    // 1) binOff[b] = sum of binFill[i] for i < b  (masked reduction, redundant per block)
    int contrib = 0;
    if (t < NBIN && t < b) contrib += binFill[t];
    int t2 = t + 256;
    if (t2 < NBIN && t2 < b) contrib += binFill[t2];
    for (int off = 32; off; off >>= 1) contrib += __shfl_down(contrib, off, 64);
    if ((t & 63) == 0) wsum[t >> 6] = contrib;
    if (t < 128) cnt[t] = 0;
    __syncthreads();
    int binOffB = wsum[0] + wsum[1] + wsum[2] + wsum[3];

    // 2) stage edges to LDS + histogram
    int n = min(binFill[b], CAP);
    for (int k = t; k < n; k += 256) {
        unsigned c = edgeBin[(size_t)b * CAP + k];
        eb[k] = c;
        atomicAdd(&cnt[c >> 17], 1);
    }
    __syncthreads();

    // 3) 128-wide inclusive scan (all threads hit barriers)
    if (t < 128) sc[t] = cnt[t];
    __syncthreads();
    for (int off = 1; off < 128; off <<= 1) {
        int v = (t < 128 && t >= off) ? sc[t - off] : 0;
        __syncthreads();
        if (t < 128) sc[t] += v;
        __syncthreads();
    }
    if (t < 128) {
        int node = b * 128 + t;
        int rs = binOffB + sc[t] - cnt[t];   // exclusive prefix
        wp[t] = rs;
        if (node < NNODES) rowstart[node] = rs;
    }
    if (b == 0 && t == 128) rowstart[NNODES] = EEDGES;
    __syncthreads();

    // 4) scatter (bin-local contiguous writes)
    for (int k = t; k < n; k += 256) {
        unsigned c = eb[k];
        int p = atomicAdd(&wp[c >> 17], 1);
        srcSorted[p] = (int)(c & 0x1FFFF);
    }
}

// ---------------- K3: gather 128 features (per-node, 8-deep MLP) ----------------
__global__ void gather_bf16(const unsigned short* __restrict__ feat,
                            const int* __restrict__ rowstart,
                            const int* __restrict__ srcSorted,
                            unsigned short* __restrict__ aggout) {
    int tid = threadIdx.x;
    int i = blockIdx.x * 4 + (tid >> 6);
    int j = tid & 63;
    const unsigned int* fp = (const unsigned int*)feat;
    int k0 = rowstart[i], k1 = rowstart[i + 1];
    float a0 = 0.0f, a1 = 0.0f;
    int k = k0;
    for (; k + 8 <= k1; k += 8) {
        int s0 = srcSorted[k],     s1 = srcSorted[k + 1], s2 = srcSorted[k + 2], s3 = srcSorted[k + 3];
        int s4 = srcSorted[k + 4], s5 = srcSorted[k + 5], s6 = srcSorted[k + 6], s7 = srcSorted[k + 7];
        unsigned int u0 = fp[(size_t)s0 * 64 + j];
        unsigned int u1 = fp[(size_t)s1 * 64 + j];
        unsigned int u2 = fp[(size_t)s2 * 64 + j];
        unsigned int u3 = fp[(size_t)s3 * 64 + j];
        unsigned int u4 = fp[(size_t)s4 * 64 + j];
        unsigned int u5 = fp[(size_t)s5 * 64 + j];
        unsigned int u6 = fp[(size_t)s6 * 64 + j];
        unsigned int u7 = fp[(size_t)s7 * 64 + j];
        a0 += lo16(u0) + lo16(u1) + lo16(u2) + lo16(u3) + lo16(u4) + lo16(u5) + lo16(u6) + lo16(u7);
        a1 += hi16(u0) + hi16(u1) + hi16(u2) + hi16(u3) + hi16(u4) + hi16(u5) + hi16(u6) + hi16(u7);
    }
    for (; k + 4 <= k1; k += 4) {
        int s0 = srcSorted[k], s1 = srcSorted[k + 1], s2 = srcSorted[k + 2], s3 = srcSorted[k + 3];
        unsigned int u0 = fp[(size_t)s0 * 64 + j];
        unsigned int u1 = fp[(size_t)s1 * 64 + j];
        unsigned int u2 = fp[(size_t)s2 * 64 + j];
        unsigned int u3 = fp[(size_t)s3 * 64 + j];
        a0 += lo16(u0) + lo16(u1) + lo16(u2) + lo16(u3);
        a1 += hi16(u0) + hi16(u1) + hi16(u2) + hi16(u3);
    }
    for (; k < k1; ++k) {
        unsigned int u = fp[(size_t)srcSorted[k] * 64 + j];
        a0 += lo16(u);
        a1 += hi16(u);
    }
    float inv = 1.0f / (float)max(k1 - k0, 1);
    ((unsigned int*)aggout)[(size_t)i * 64 + j] = packbf(a0 * inv, a1 * inv);
}

// ---------------- K4: lin1 persistent-weight MFMA + fused BN partials ----------------
__global__ void __launch_bounds__(256, 2)
lin1_persist(const unsigned short* __restrict__ aggb,
             const unsigned short* __restrict__ xb,
             const unsigned short* __restrict__ wl,
             const unsigned short* __restrict__ wr,
             const float* __restrict__ bias,
             unsigned short* __restrict__ hb,
             float* __restrict__ bnsum, float* __restrict__ bnsq) {
    __shared__ float bps[128];
    __shared__ float bpq[128];
    int tid = threadIdx.x;
    if (tid < 128) { bps[tid] = 0.0f; bpq[tid] = 0.0f; }
    __syncthreads();
    int wave = tid >> 6;
    int lane = tid & 63;
    int c = wave & 1;
    int rsub = wave >> 1;
    int lrow = lane & 15;
    int kg = lane >> 4;

    bf16x8 wlF[4][4], wrF[4][4];
    #pragma unroll
    for (int nf = 0; nf < 4; ++nf) {
        #pragma unroll
        for (int ks = 0; ks < 4; ++ks) {
            wlF[nf][ks] = *(const bf16x8*)(wl + (size_t)(c * 64 + nf * 16 + lrow) * 128 + ks * 32 + kg * 8);
            wrF[nf][ks] = *(const bf16x8*)(wr + (size_t)(c * 64 + nf * 16 + lrow) * 128 + ks * 32 + kg * 8);
        }
    }
    float bias_v[4];
    #pragma unroll
    for (int nf = 0; nf < 4; ++nf) bias_v[nf] = bias[c * 64 + nf * 16 + lrow];

    for (int tIt = blockIdx.x; tIt < NTILES; tIt += gridDim.x) {
        int rowA = tIt * 32 + rsub * 16 + lrow;
        int arow = min(rowA, NNODES - 1);
        bf16x8 aA[4], aX[4];
        #pragma unroll
        for (int ks = 0; ks < 4; ++ks) {
            aA[ks] = *(const bf16x8*)(aggb + (size_t)arow * 128 + ks * 32 + kg * 8);
            aX[ks] = *(const bf16x8*)(xb + (size_t)arow * 128 + ks * 32 + kg * 8);
        }
        f32x4 acc[4] = {};
        #pragma unroll
        for (int ks = 0; ks < 4; ++ks) {
            #pragma unroll
            for (int nf = 0; nf < 4; ++nf) {
                acc[nf] = __builtin_amdgcn_mfma_f32_16x16x32_bf16(aA[ks], wlF[nf][ks], acc[nf], 0, 0, 0);
                acc[nf] = __builtin_amdgcn_mfma_f32_16x16x32_bf16(aX[ks], wrF[nf][ks], acc[nf], 0, 0, 0);
            }
        }
        #pragma unroll
        for (int nf = 0; nf < 4; ++nf) {
            float s = 0.0f, q = 0.0f;
            #pragma unroll
            for (int rr = 0; rr < 4; ++rr) {
                int row = tIt * 32 + rsub * 16 + kg * 4 + rr;
                if (row < NNODES) {
                    unsigned short hv = tobf16(acc[nf][rr] + bias_v[nf]);
                    float vr = frombf16(hv);
                    hb[(size_t)row * 128 + c * 64 + nf * 16 + lrow] = hv;
                    s += vr; q += vr * vr;
                }
            }
            s += __shfl_xor(s, 16); s += __shfl_xor(s, 32);
            q += __shfl_xor(q, 16); q += __shfl_xor(q, 32);
            if (lane < 16) {
                atomicAdd(&bps[c * 64 + nf * 16 + lane], s);
                atomicAdd(&bpq[c * 64 + nf * 16 + lane], q);
            }
        }
    }
    __syncthreads();
    if (tid < 128) {
        atomicAdd(&bnsum[tid], bps[tid]);
        atomicAdd(&bnsq[tid], bpq[tid]);
    }
}

// ---------------- K5: fused BN apply + PReLU + residual + y2 = h'@Wl2^T ----------------
__global__ void bn_lin2a_kernel(unsigned short* __restrict__ hb,
                                const unsigned short* __restrict__ xb,
                                const float* __restrict__ gamma, const float* __restrict__ beta,
                                const float* __restrict__ aptr,
                                const float* __restrict__ bnsum, const float* __restrict__ bnsq,
                                const unsigned short* __restrict__ wl,
                                unsigned short* __restrict__ y2) {
    __shared__ float scs[128];
    __shared__ float shs[128];
    int tid = threadIdx.x;
    if (tid < 128) {
        const float invN = 1.0f / (float)NNODES;
        float mean = bnsum[tid] * invN;
        float var = bnsq[tid] * invN - mean * mean;
        float istd = rsqrtf(var + BN_EPS);
        float sc = gamma[tid] * istd;
        scs[tid] = sc;
        shs[tid] = beta[tid] - mean * sc;
    }
    __syncthreads();
    float aP = aptr[0];
    int wave = tid >> 6;
    int lane = tid & 63;
    int row0 = blockIdx.x * 64 + wave * 16;
    int lrow = lane & 15;
    int kg = lane >> 4;
    int rowA = row0 + lrow;
    int arow = min(rowA, NNODES - 1);
    f32x4 acc = {};
    #pragma unroll
    for (int ks = 0; ks < 4; ++ks) {
        bf16x8 hv = *(const bf16x8*)(hb + (size_t)arow * 128 + ks * 32 + kg * 8);
        bf16x8 xv = *(const bf16x8*)(xb + (size_t)arow * 128 + ks * 32 + kg * 8);
        bf16x8 nv;
        #pragma unroll
        for (int e = 0; e < 8; ++e) {
            int f = ks * 32 + kg * 8 + e;
            float v = frombf16((unsigned short)hv[e]) * scs[f] + shs[f];
            v = (v >= 0.0f) ? v : aP * v;
            v += frombf16((unsigned short)xv[e]);
            nv[e] = (short)tobf16(v);
        }
        if (rowA < NNODES)
            *(bf16x8*)(hb + (size_t)arow * 128 + ks * 32 + kg * 8) = nv;
        bf16x8 b = *(const bf16x8*)(wl + (size_t)lrow * 128 + ks * 32 + kg * 8);
        acc = __builtin_amdgcn_mfma_f32_16x16x32_bf16(nv, b, acc, 0, 0, 0);
    }
    #pragma unroll
    for (int r = 0; r < 4; ++r) {
        int row = row0 + kg * 4 + r;
        if (row < NNODES)
            y2[(size_t)row * 16 + lrow] = tobf16(acc[r]);
    }
}

// ---------------- K6: fused gather16 (LDS) + lin2b + log_softmax ----------------
__global__ void gather16_lin2b_kernel(const unsigned short* __restrict__ y2,
                                      const int* __restrict__ rowstart,
                                      const int* __restrict__ srcSorted,
                                      const unsigned short* __restrict__ hb,
                                      const unsigned short* __restrict__ wr,
                                      const float* __restrict__ bias,
                                      float* __restrict__ out) {
    __shared__ float agg[64][16];
    int t = threadIdx.x;
    int w = t >> 6;
    int lane = t & 63;
    int e = lane >> 3;
    int j = lane & 7;
    const unsigned int* yp = (const unsigned int*)y2;
    int nodeBase = blockIdx.x * 64;

    // phase 1: gather agg2 for 16 nodes per wave into LDS (fp32)
    for (int it = 0; it < 16; ++it) {
        int i = nodeBase + w * 16 + it;
        int ic = min(i, NNODES - 1);
        int k0 = rowstart[ic], k1 = rowstart[ic + 1];
        float a0 = 0.0f, a1 = 0.0f;
        for (int k = k0; k < k1; k += 8) {
            int kk = k + e;
            if (kk < k1) {
                unsigned u = yp[(size_t)srcSorted[kk] * 8 + j];
                a0 += lo16(u);
                a1 += hi16(u);
            }
        }
        a0 += __shfl_xor(a0, 8);  a1 += __shfl_xor(a1, 8);
        a0 += __shfl_xor(a0, 16); a1 += __shfl_xor(a1, 16);
        a0 += __shfl_xor(a0, 32); a1 += __shfl_xor(a1, 32);
        if (e == 0) {
            float inv = 1.0f / (float)max(k1 - k0, 1);
            agg[w * 16 + it][2 * j]     = a0 * inv;
            agg[w * 16 + it][2 * j + 1] = a1 * inv;
        }
    }
    __syncthreads();

    // phase 2: out = agg2 + hb@Wr2^T + bl2 -> log_softmax
    int lrow = lane & 15;
    int kg = lane >> 4;
    int row0 = nodeBase + w * 16;
    int arow = min(row0 + lrow, NNODES - 1);
    f32x4 acc = {};
    #pragma unroll
    for (int ks = 0; ks < 4; ++ks) {
        bf16x8 a = *(const bf16x8*)(hb + (size_t)arow * 128 + ks * 32 + kg * 8);
        bf16x8 b = *(const bf16x8*)(wr + (size_t)lrow * 128 + ks * 32 + kg * 8);
        acc = __builtin_amdgcn_mfma_f32_16x16x32_bf16(a, b, acc, 0, 0, 0);
    }
    float bl = bias[lrow];
    #pragma unroll
    for (int r = 0; r < 4; ++r) {
        int row = row0 + kg * 4 + r;
        int lr = w * 16 + kg * 4 + r;
        float v = acc[r] + bl + agg[lr][lrow];
        float m = v;
        for (int s = 1; s < 16; s <<= 1) m = fmaxf(m, __shfl_xor(m, s, 16));
        float ex = expf(v - m);
        float se = ex;
        for (int s = 1; s < 16; s <<= 1) se += __shfl_xor(se, s, 16);
        if (row < NNODES)
            out[(size_t)row * FOUT + lrow] = v - m - logf(se);
    }
}

extern "C" void kernel_launch(void* const* d_in, const int* in_sizes, int n_in,
                              void* d_out, int out_size, void* d_ws, size_t ws_size,
                              hipStream_t stream) {
    const float* x    = (const float*)d_in[0];
    const int*   ei   = (const int*)d_in[1];
    const int*   src  = ei;
    const int*   dst  = ei + EEDGES;
    const float* Wl1  = (const float*)d_in[2];
    const float* bl1  = (const float*)d_in[3];
    const float* Wr1  = (const float*)d_in[4];
    const float* Wl2  = (const float*)d_in[5];
    const float* bl2  = (const float*)d_in[6];
    const float* Wr2  = (const float*)d_in[7];
    const float* gamma= (const float*)d_in[8];
    const float* beta = (const float*)d_in[9];
    const float* a    = (const float*)d_in[10];
    float* out = (float*)d_out;

    char* W = (char*)d_ws;
    unsigned short* xb    = (unsigned short*)(W + 0);           // 12,800,000 B
    unsigned short* hb    = (unsigned short*)(W + 12800000);    // 12,800,000 B
    unsigned int*  edgeBin= (unsigned int*)(W + 25600000);      // 6,406,144 B (dead after K2)
    unsigned short* aggb  = (unsigned short*)(W + 25600000);    // 12,800,000 B (overlays edgeBin)
    unsigned short* y2b   = (unsigned short*)(W + 25600000);    // 1,600,000 B (overlays aggb)
    unsigned short* wb    = (unsigned short*)(W + 38400000);    // 73,728 B
    int* binFill  = (int*)(W + 38473728);                       // 1,564 B
    float* bnsum  = (float*)(W + 38475292);                     // 512 B
    float* bnsq   = (float*)(W + 38475804);                     // 512 B
    int* rowstart = (int*)(W + 38678072);                       // 200,004 B
    int* srcSorted= (int*)(W + 38878076);                       // 3,200,000 B

    unsigned short* wl1b = wb;
    unsigned short* wr1b = wb + 16384;
    unsigned short* wl2b = wb + 32768;
    unsigned short* wr2b = wb + 34816;

    // zero binFill + bnsum + bnsq (contiguous 2,588 B)
    hipMemsetAsync(binFill, 0, (size_t)2588, stream);

    part_pack_kernel<<<NPB + PACKBLKS, 256, 0, stream>>>(src, dst, binFill, edgeBin,
                                                         x, Wl1, Wr1, Wl2, Wr2, xb, wb);
    bucket_fused_kernel<<<NBIN, 256, 0, stream>>>(edgeBin, binFill, srcSorted, rowstart);

    // layer 1
    gather_bf16<<<NNODES / 4, 256, 0, stream>>>(xb, rowstart, srcSorted, aggb);
    lin1_persist<<<512, 256, 0, stream>>>(aggb, xb, wl1b, wr1b, bl1, hb, bnsum, bnsq);

    // fused BN/PReLU/residual + lin2a
    bn_lin2a_kernel<<<782, 256, 0, stream>>>(hb, xb, gamma, beta, a, bnsum, bnsq, wl2b, y2b);

    // fused layer-2 aggregate + final linear + log_softmax
    gather16_lin2b_kernel<<<782, 256, 0, stream>>>(y2b, rowstart, srcSorted, hb, wr2b, bl2, out);
}

// Round 12
// 146.398 us; speedup vs baseline: 1.0705x; 1.0705x over previous
//
#include <hip/hip_runtime.h>

#define NNODES 50000
#define EEDGES 800000
#define FIN 128
#define FH 128
#define FOUT 16
#define BN_EPS 1e-5f
#define NBIN 391      // ceil(50000/128) bins of 128 dst nodes
#define CAP 4096      // fixed edge capacity per bin (expected ~2048, max ~2250)
#define PCH 2048      // edges per partition block
#define NPB 391       // ceil(800000/2048)
#define NTILES 1563   // ceil(50000/32) lin1 row tiles
#define PACKBLKS 3143 // 6,436,864 elems / (256*8)

typedef short bf16x8 __attribute__((ext_vector_type(8)));
typedef float f32x4 __attribute__((ext_vector_type(4)));

__device__ inline unsigned short tobf16(float f) {
    unsigned int u = __float_as_uint(f);
    u += 0x7fffu + ((u >> 16) & 1u);   // RNE
    return (unsigned short)(u >> 16);
}
__device__ inline float frombf16(unsigned short h) {
    return __uint_as_float(((unsigned int)h) << 16);
}
__device__ inline unsigned packbf(float f0, float f1) {
    return (unsigned)tobf16(f0) | ((unsigned)tobf16(f1) << 16);
}
__device__ inline float lo16(unsigned u) { return __uint_as_float(u << 16); }
__device__ inline float hi16(unsigned u) { return __uint_as_float(u & 0xffff0000u); }

// ---------------- K0: zero binFill+bnsum+bnsq (replaces rocclr fillBuffer) ----------------
__global__ void zero_kernel(int* __restrict__ p) {
    for (int i = threadIdx.x; i < 647; i += 256) p[i] = 0;
}

// ---------------- K1: partition (blocks 0..390) || pack (blocks 391..) ----------------
__global__ void part_pack_kernel(const int* __restrict__ src, const int* __restrict__ dst,
                                 int* __restrict__ binFill, unsigned int* __restrict__ edgeBin,
                                 const float* __restrict__ x,
                                 const float* __restrict__ Wl1, const float* __restrict__ Wr1,
                                 const float* __restrict__ Wl2, const float* __restrict__ Wr2,
                                 unsigned short* __restrict__ xb, unsigned short* __restrict__ wb) {
    __shared__ int hist[NBIN];
    __shared__ int runBase[NBIN];
    __shared__ int runFill[NBIN];
    int t = threadIdx.x;
    if (blockIdx.x < NPB) {
        // ---- partition path ----
        for (int i = t; i < NBIN; i += 256) { hist[i] = 0; runFill[i] = 0; }
        __syncthreads();
        int e0 = blockIdx.x * PCH;
        for (int i = 0; i < PCH / 256; ++i) {
            int e = e0 + i * 256 + t;
            if (e < EEDGES) atomicAdd(&hist[dst[e] >> 7], 1);
        }
        __syncthreads();
        for (int i = t; i < NBIN; i += 256) {
            int c = hist[i];
            if (c) runBase[i] = atomicAdd(&binFill[i], c);
        }
        __syncthreads();
        for (int i = 0; i < PCH / 256; ++i) {
            int e = e0 + i * 256 + t;
            if (e < EEDGES) {
                int d = dst[e];
                int b = d >> 7;
                int off = runBase[b] + atomicAdd(&runFill[b], 1);
                if (off < CAP)
                    edgeBin[(size_t)b * CAP + off] = ((unsigned)(d & 127) << 17) | (unsigned)src[e];
            }
        }
    } else {
        // ---- pack path: 8 elems/thread ----
        int tt = (blockIdx.x - NPB) * 256 + t;
        int base = tt * 8;
        const float* srcp;
        unsigned short* dstp;
        int off;
        if (base < NNODES * FIN) {
            srcp = x; off = base; dstp = xb + base;
        } else {
            int w = base - NNODES * FIN;
            if (w >= 36864) return;
            dstp = wb + w;
            if (w < 16384)      { srcp = Wl1; off = w; }
            else if (w < 32768) { srcp = Wr1; off = w - 16384; }
            else if (w < 34816) { srcp = Wl2; off = w - 32768; }
            else                { srcp = Wr2; off = w - 34816; }
        }
        float4 f0 = *reinterpret_cast<const float4*>(srcp + off);
        float4 f1 = *reinterpret_cast<const float4*>(srcp + off + 4);
        uint4 r;
        r.x = packbf(f0.x, f0.y);
        r.y = packbf(f0.z, f0.w);
        r.z = packbf(f1.x, f1.y);
        r.w = packbf(f1.z, f1.w);
        *reinterpret_cast<uint4*>(dstp) = r;
    }
}

// ---------------- K2: fused bucket: binOff reduction + LDS histogram/scan + scatter --------
__global__ void bucket_fused_kernel(const unsigned int* __restrict__ edgeBin,
                                    const int* __restrict__ binFill,
                                    int* __restrict__ srcSorted,
                                    int* __restrict__ rowstart) {
    __shared__ unsigned eb[CAP];     // 16 KB staging of this bin's edges
    __shared__ int cnt[128];
    __shared__ int sc[128];
    __shared__ int wp[128];
    __shared__ int wsum[4];
    int b = blockIdx.x;
    int t = threadIdx.x;

    // 1) binOff[b] = sum of binFill[i] for i < b  (masked reduction, redundant per block)
    int contrib = 0;
    if (t < NBIN && t < b) contrib += binFill[t];
    int t2 = t + 256;
    if (t2 < NBIN && t2 < b) contrib += binFill[t2];
    for (int off = 32; off; off >>= 1) contrib += __shfl_down(contrib, off, 64);
    if ((t & 63) == 0) wsum[t >> 6] = contrib;
    if (t < 128) cnt[t] = 0;
    __syncthreads();
    int binOffB = wsum[0] + wsum[1] + wsum[2] + wsum[3];

    // 2) stage edges to LDS + histogram
    int n = min(binFill[b], CAP);
    for (int k = t; k < n; k += 256) {
        unsigned c = edgeBin[(size_t)b * CAP + k];
        eb[k] = c;
        atomicAdd(&cnt[c >> 17], 1);
    }
    __syncthreads();

    // 3) 128-wide inclusive scan (all threads hit barriers)
    if (t < 128) sc[t] = cnt[t];
    __syncthreads();
    for (int off = 1; off < 128; off <<= 1) {
        int v = (t < 128 && t >= off) ? sc[t - off] : 0;
        __syncthreads();
        if (t < 128) sc[t] += v;
        __syncthreads();
    }
    if (t < 128) {
        int node = b * 128 + t;
        int rs = binOffB + sc[t] - cnt[t];   // exclusive prefix
        wp[t] = rs;
        if (node < NNODES) rowstart[node] = rs;
    }
    if (b == 0 && t == 128) rowstart[NNODES] = EEDGES;
    __syncthreads();

    // 4) scatter (bin-local contiguous writes)
    for (int k = t; k < n; k += 256) {
        unsigned c = eb[k];
        int p = atomicAdd(&wp[c >> 17], 1);
        srcSorted[p] = (int)(c & 0x1FFFF);
    }
}

// ---------------- K3: gather 128 features (per-node, 8-deep MLP) ----------------
__global__ void gather_bf16(const unsigned short* __restrict__ feat,
                            const int* __restrict__ rowstart,
                            const int* __restrict__ srcSorted,
                            unsigned short* __restrict__ aggout) {
    int tid = threadIdx.x;
    int i = blockIdx.x * 4 + (tid >> 6);
    int j = tid & 63;
    const unsigned int* fp = (const unsigned int*)feat;
    int k0 = rowstart[i], k1 = rowstart[i + 1];
    float a0 = 0.0f, a1 = 0.0f;
    int k = k0;
    for (; k + 8 <= k1; k += 8) {
        int s0 = srcSorted[k],     s1 = srcSorted[k + 1], s2 = srcSorted[k + 2], s3 = srcSorted[k + 3];
        int s4 = srcSorted[k + 4], s5 = srcSorted[k + 5], s6 = srcSorted[k + 6], s7 = srcSorted[k + 7];
        unsigned int u0 = fp[(size_t)s0 * 64 + j];
        unsigned int u1 = fp[(size_t)s1 * 64 + j];
        unsigned int u2 = fp[(size_t)s2 * 64 + j];
        unsigned int u3 = fp[(size_t)s3 * 64 + j];
        unsigned int u4 = fp[(size_t)s4 * 64 + j];
        unsigned int u5 = fp[(size_t)s5 * 64 + j];
        unsigned int u6 = fp[(size_t)s6 * 64 + j];
        unsigned int u7 = fp[(size_t)s7 * 64 + j];
        a0 += lo16(u0) + lo16(u1) + lo16(u2) + lo16(u3) + lo16(u4) + lo16(u5) + lo16(u6) + lo16(u7);
        a1 += hi16(u0) + hi16(u1) + hi16(u2) + hi16(u3) + hi16(u4) + hi16(u5) + hi16(u6) + hi16(u7);
    }
    for (; k + 4 <= k1; k += 4) {
        int s0 = srcSorted[k], s1 = srcSorted[k + 1], s2 = srcSorted[k + 2], s3 = srcSorted[k + 3];
        unsigned int u0 = fp[(size_t)s0 * 64 + j];
        unsigned int u1 = fp[(size_t)s1 * 64 + j];
        unsigned int u2 = fp[(size_t)s2 * 64 + j];
        unsigned int u3 = fp[(size_t)s3 * 64 + j];
        a0 += lo16(u0) + lo16(u1) + lo16(u2) + lo16(u3);
        a1 += hi16(u0) + hi16(u1) + hi16(u2) + hi16(u3);
    }
    for (; k < k1; ++k) {
        unsigned int u = fp[(size_t)srcSorted[k] * 64 + j];
        a0 += lo16(u);
        a1 += hi16(u);
    }
    float inv = 1.0f / (float)max(k1 - k0, 1);
    ((unsigned int*)aggout)[(size_t)i * 64 + j] = packbf(a0 * inv, a1 * inv);
}

// ---------------- K4: lin1 persistent-weight MFMA + fused BN partials ----------------
__global__ void __launch_bounds__(256, 2)
lin1_persist(const unsigned short* __restrict__ aggb,
             const unsigned short* __restrict__ xb,
             const unsigned short* __restrict__ wl,
             const unsigned short* __restrict__ wr,
             const float* __restrict__ bias,
             unsigned short* __restrict__ hb,
             float* __restrict__ bnsum, float* __restrict__ bnsq) {
    __shared__ float bps[128];
    __shared__ float bpq[128];
    int tid = threadIdx.x;
    if (tid < 128) { bps[tid] = 0.0f; bpq[tid] = 0.0f; }
    __syncthreads();
    int wave = tid >> 6;
    int lane = tid & 63;
    int c = wave & 1;
    int rsub = wave >> 1;
    int lrow = lane & 15;
    int kg = lane >> 4;

    bf16x8 wlF[4][4], wrF[4][4];
    #pragma unroll
    for (int nf = 0; nf < 4; ++nf) {
        #pragma unroll
        for (int ks = 0; ks < 4; ++ks) {
            wlF[nf][ks] = *(const bf16x8*)(wl + (size_t)(c * 64 + nf * 16 + lrow) * 128 + ks * 32 + kg * 8);
            wrF[nf][ks] = *(const bf16x8*)(wr + (size_t)(c * 64 + nf * 16 + lrow) * 128 + ks * 32 + kg * 8);
        }
    }
    float bias_v[4];
    #pragma unroll
    for (int nf = 0; nf < 4; ++nf) bias_v[nf] = bias[c * 64 + nf * 16 + lrow];

    for (int tIt = blockIdx.x; tIt < NTILES; tIt += gridDim.x) {
        int rowA = tIt * 32 + rsub * 16 + lrow;
        int arow = min(rowA, NNODES - 1);
        bf16x8 aA[4], aX[4];
        #pragma unroll
        for (int ks = 0; ks < 4; ++ks) {
            aA[ks] = *(const bf16x8*)(aggb + (size_t)arow * 128 + ks * 32 + kg * 8);
            aX[ks] = *(const bf16x8*)(xb + (size_t)arow * 128 + ks * 32 + kg * 8);
        }
        f32x4 acc[4] = {};
        #pragma unroll
        for (int ks = 0; ks < 4; ++ks) {
            #pragma unroll
            for (int nf = 0; nf < 4; ++nf) {
                acc[nf] = __builtin_amdgcn_mfma_f32_16x16x32_bf16(aA[ks], wlF[nf][ks], acc[nf], 0, 0, 0);
                acc[nf] = __builtin_amdgcn_mfma_f32_16x16x32_bf16(aX[ks], wrF[nf][ks], acc[nf], 0, 0, 0);
            }
        }
        #pragma unroll
        for (int nf = 0; nf < 4; ++nf) {
            float s = 0.0f, q = 0.0f;
            #pragma unroll
            for (int rr = 0; rr < 4; ++rr) {
                int row = tIt * 32 + rsub * 16 + kg * 4 + rr;
                if (row < NNODES) {
                    unsigned short hv = tobf16(acc[nf][rr] + bias_v[nf]);
                    float vr = frombf16(hv);
                    hb[(size_t)row * 128 + c * 64 + nf * 16 + lrow] = hv;
                    s += vr; q += vr * vr;
                }
            }
            s += __shfl_xor(s, 16); s += __shfl_xor(s, 32);
            q += __shfl_xor(q, 16); q += __shfl_xor(q, 32);
            if (lane < 16) {
                atomicAdd(&bps[c * 64 + nf * 16 + lane], s);
                atomicAdd(&bpq[c * 64 + nf * 16 + lane], q);
            }
        }
    }
    __syncthreads();
    if (tid < 128) {
        atomicAdd(&bnsum[tid], bps[tid]);
        atomicAdd(&bnsq[tid], bpq[tid]);
    }
}

// ---------------- K5: fused BN apply + PReLU + residual + y2 = h'@Wl2^T ----------------
__global__ void bn_lin2a_kernel(unsigned short* __restrict__ hb,
                                const unsigned short* __restrict__ xb,
                                const float* __restrict__ gamma, const float* __restrict__ beta,
                                const float* __restrict__ aptr,
                                const float* __restrict__ bnsum, const float* __restrict__ bnsq,
                                const unsigned short* __restrict__ wl,
                                unsigned short* __restrict__ y2) {
    __shared__ float scs[128];
    __shared__ float shs[128];
    int tid = threadIdx.x;
    if (tid < 128) {
        const float invN = 1.0f / (float)NNODES;
        float mean = bnsum[tid] * invN;
        float var = bnsq[tid] * invN - mean * mean;
        float istd = rsqrtf(var + BN_EPS);
        float sc = gamma[tid] * istd;
        scs[tid] = sc;
        shs[tid] = beta[tid] - mean * sc;
    }
    __syncthreads();
    float aP = aptr[0];
    int wave = tid >> 6;
    int lane = tid & 63;
    int row0 = blockIdx.x * 64 + wave * 16;
    int lrow = lane & 15;
    int kg = lane >> 4;
    int rowA = row0 + lrow;
    int arow = min(rowA, NNODES - 1);
    f32x4 acc = {};
    #pragma unroll
    for (int ks = 0; ks < 4; ++ks) {
        bf16x8 hv = *(const bf16x8*)(hb + (size_t)arow * 128 + ks * 32 + kg * 8);
        bf16x8 xv = *(const bf16x8*)(xb + (size_t)arow * 128 + ks * 32 + kg * 8);
        bf16x8 nv;
        #pragma unroll
        for (int e = 0; e < 8; ++e) {
            int f = ks * 32 + kg * 8 + e;
            float v = frombf16((unsigned short)hv[e]) * scs[f] + shs[f];
            v = (v >= 0.0f) ? v : aP * v;
            v += frombf16((unsigned short)xv[e]);
            nv[e] = (short)tobf16(v);
        }
        if (rowA < NNODES)
            *(bf16x8*)(hb + (size_t)arow * 128 + ks * 32 + kg * 8) = nv;
        bf16x8 b = *(const bf16x8*)(wl + (size_t)lrow * 128 + ks * 32 + kg * 8);
        acc = __builtin_amdgcn_mfma_f32_16x16x32_bf16(nv, b, acc, 0, 0, 0);
    }
    #pragma unroll
    for (int r = 0; r < 4; ++r) {
        int row = row0 + kg * 4 + r;
        if (row < NNODES)
            y2[(size_t)row * 16 + lrow] = tobf16(acc[r]);
    }
}

// ---------------- K6: fused gather16 (LDS) + lin2b + log_softmax ----------------
__global__ void gather16_lin2b_kernel(const unsigned short* __restrict__ y2,
                                      const int* __restrict__ rowstart,
                                      const int* __restrict__ srcSorted,
                                      const unsigned short* __restrict__ hb,
                                      const unsigned short* __restrict__ wr,
                                      const float* __restrict__ bias,
                                      float* __restrict__ out) {
    __shared__ float agg[64][16];
    int t = threadIdx.x;
    int w = t >> 6;
    int lane = t & 63;
    int e = lane >> 3;
    int j = lane & 7;
    const unsigned int* yp = (const unsigned int*)y2;
    int nodeBase = blockIdx.x * 64;

    // phase 1: gather agg2 for 16 nodes per wave into LDS (fp32)
    for (int it = 0; it < 16; ++it) {
        int i = nodeBase + w * 16 + it;
        int ic = min(i, NNODES - 1);
        int k0 = rowstart[ic], k1 = rowstart[ic + 1];
        float a0 = 0.0f, a1 = 0.0f;
        for (int k = k0; k < k1; k += 8) {
            int kk = k + e;
            if (kk < k1) {
                unsigned u = yp[(size_t)srcSorted[kk] * 8 + j];
                a0 += lo16(u);
                a1 += hi16(u);
            }
        }
        a0 += __shfl_xor(a0, 8);  a1 += __shfl_xor(a1, 8);
        a0 += __shfl_xor(a0, 16); a1 += __shfl_xor(a1, 16);
        a0 += __shfl_xor(a0, 32); a1 += __shfl_xor(a1, 32);
        if (e == 0) {
            float inv = 1.0f / (float)max(k1 - k0, 1);
            agg[w * 16 + it][2 * j]     = a0 * inv;
            agg[w * 16 + it][2 * j + 1] = a1 * inv;
        }
    }
    __syncthreads();

    // phase 2: out = agg2 + hb@Wr2^T + bl2 -> log_softmax
    int lrow = lane & 15;
    int kg = lane >> 4;
    int row0 = nodeBase + w * 16;
    int arow = min(row0 + lrow, NNODES - 1);
    f32x4 acc = {};
    #pragma unroll
    for (int ks = 0; ks < 4; ++ks) {
        bf16x8 a = *(const bf16x8*)(hb + (size_t)arow * 128 + ks * 32 + kg * 8);
        bf16x8 b = *(const bf16x8*)(wr + (size_t)lrow * 128 + ks * 32 + kg * 8);
        acc = __builtin_amdgcn_mfma_f32_16x16x32_bf16(a, b, acc, 0, 0, 0);
    }
    float bl = bias[lrow];
    #pragma unroll
    for (int r = 0; r < 4; ++r) {
        int row = row0 + kg * 4 + r;
        int lr = w * 16 + kg * 4 + r;
        float v = acc[r] + bl + agg[lr][lrow];
        float m = v;
        for (int s = 1; s < 16; s <<= 1) m = fmaxf(m, __shfl_xor(m, s, 16));
        float ex = expf(v - m);
        float se = ex;
        for (int s = 1; s < 16; s <<= 1) se += __shfl_xor(se, s, 16);
        if (row < NNODES)
            out[(size_t)row * FOUT + lrow] = v - m - logf(se);
    }
}

extern "C" void kernel_launch(void* const* d_in, const int* in_sizes, int n_in,
                              void* d_out, int out_size, void* d_ws, size_t ws_size,
                              hipStream_t stream) {
    const float* x    = (const float*)d_in[0];
    const int*   ei   = (const int*)d_in[1];
    const int*   src  = ei;
    const int*   dst  = ei + EEDGES;
    const float* Wl1  = (const float*)d_in[2];
    const float* bl1  = (const float*)d_in[3];
    const float* Wr1  = (const float*)d_in[4];
    const float* Wl2  = (const float*)d_in[5];
    const float* bl2  = (const float*)d_in[6];
    const float* Wr2  = (const float*)d_in[7];
    const float* gamma= (const float*)d_in[8];
    const float* beta = (const float*)d_in[9];
    const float* a    = (const float*)d_in[10];
    float* out = (float*)d_out;

    char* W = (char*)d_ws;
    unsigned short* xb    = (unsigned short*)(W + 0);           // 12,800,000 B
    unsigned short* hb    = (unsigned short*)(W + 12800000);    // 12,800,000 B
    unsigned int*  edgeBin= (unsigned int*)(W + 25600000);      // 6,406,144 B (dead after K2)
    unsigned short* aggb  = (unsigned short*)(W + 25600000);    // 12,800,000 B (overlays edgeBin)
    unsigned short* y2b   = (unsigned short*)(W + 25600000);    // 1,600,000 B (overlays aggb)
    unsigned short* wb    = (unsigned short*)(W + 38400000);    // 73,728 B
    int* binFill  = (int*)(W + 38473728);                       // 1,564 B
    float* bnsum  = (float*)(W + 38475292);                     // 512 B
    float* bnsq   = (float*)(W + 38475804);                     // 512 B
    int* rowstart = (int*)(W + 38678072);                       // 200,004 B
    int* srcSorted= (int*)(W + 38878076);                       // 3,200,000 B

    unsigned short* wl1b = wb;
    unsigned short* wr1b = wb + 16384;
    unsigned short* wl2b = wb + 32768;
    unsigned short* wr2b = wb + 34816;

    // zero binFill + bnsum + bnsq (contiguous 2,588 B = 647 ints) — own kernel, not rocclr fill
    zero_kernel<<<1, 256, 0, stream>>>(binFill);

    part_pack_kernel<<<NPB + PACKBLKS, 256, 0, stream>>>(src, dst, binFill, edgeBin,
                                                         x, Wl1, Wr1, Wl2, Wr2, xb, wb);
    bucket_fused_kernel<<<NBIN, 256, 0, stream>>>(edgeBin, binFill, srcSorted, rowstart);

    // layer 1
    gather_bf16<<<NNODES / 4, 256, 0, stream>>>(xb, rowstart, srcSorted, aggb);
    lin1_persist<<<512, 256, 0, stream>>>(aggb, xb, wl1b, wr1b, bl1, hb, bnsum, bnsq);

    // fused BN/PReLU/residual + lin2a
    bn_lin2a_kernel<<<782, 256, 0, stream>>>(hb, xb, gamma, beta, a, bnsum, bnsq, wl2b, y2b);

    // fused layer-2 aggregate + final linear + log_softmax
    gather16_lin2b_kernel<<<782, 256, 0, stream>>>(y2b, rowstart, srcSorted, hb, wr2b, bl2, out);
}

// Round 13
// 138.538 us; speedup vs baseline: 1.1312x; 1.0567x over previous
//
#include <hip/hip_runtime.h>

#define NNODES 50000
#define EEDGES 800000
#define FIN 128
#define FH 128
#define FOUT 16
#define BN_EPS 1e-5f
#define NBIN 391      // ceil(50000/128) bins of 128 dst nodes
#define CAP 4096      // fixed edge capacity per bin (expected ~2048, max ~2250)
#define PCH 2048      // edges per partition block
#define NPB 391       // ceil(800000/2048)
#define NTILES 1563   // ceil(50000/32) lin1 row tiles
#define PACKBLKS 3143 // 6,436,864 elems / (256*8)

typedef short bf16x8 __attribute__((ext_vector_type(8)));
typedef float f32x4 __attribute__((ext_vector_type(4)));

__device__ inline unsigned short tobf16(float f) {
    unsigned int u = __float_as_uint(f);
    u += 0x7fffu + ((u >> 16) & 1u);   // RNE
    return (unsigned short)(u >> 16);
}
__device__ inline float frombf16(unsigned short h) {
    return __uint_as_float(((unsigned int)h) << 16);
}
__device__ inline unsigned packbf(float f0, float f1) {
    return (unsigned)tobf16(f0) | ((unsigned)tobf16(f1) << 16);
}
__device__ inline float lo16(unsigned u) { return __uint_as_float(u << 16); }
__device__ inline float hi16(unsigned u) { return __uint_as_float(u & 0xffff0000u); }

// ---------------- K0: zero binFill+bnsum+bnsq ----------------
__global__ void zero_kernel(int* __restrict__ p) {
    for (int i = threadIdx.x; i < 647; i += 256) p[i] = 0;
}

// ---------------- K1: partition (blocks 0..390, per-wave hist) || pack ----------------
__global__ void part_pack_kernel(const int* __restrict__ src, const int* __restrict__ dst,
                                 int* __restrict__ binFill, unsigned int* __restrict__ edgeBin,
                                 const float* __restrict__ x,
                                 const float* __restrict__ Wl1, const float* __restrict__ Wr1,
                                 const float* __restrict__ Wl2, const float* __restrict__ Wr2,
                                 unsigned short* __restrict__ xb, unsigned short* __restrict__ wb) {
    __shared__ int hist4[4][NBIN];   // per-wave histograms -> per-wave write cursors
    int t = threadIdx.x;
    if (blockIdx.x < NPB) {
        // ---- partition path ----
        int w = t >> 6;
        for (int i = t; i < NBIN; i += 256) {
            hist4[0][i] = 0; hist4[1][i] = 0; hist4[2][i] = 0; hist4[3][i] = 0;
        }
        __syncthreads();
        int e0 = blockIdx.x * PCH;
        for (int i = 0; i < PCH / 256; ++i) {
            int e = e0 + i * 256 + t;
            if (e < EEDGES) atomicAdd(&hist4[w][dst[e] >> 7], 1);
        }
        __syncthreads();
        // reserve one global run per (block,bin); carve per-wave sub-runs
        for (int i = t; i < NBIN; i += 256) {
            int h0 = hist4[0][i], h1 = hist4[1][i], h2 = hist4[2][i], h3 = hist4[3][i];
            int c = h0 + h1 + h2 + h3;
            int base = c ? atomicAdd(&binFill[i], c) : 0;
            hist4[0][i] = base;
            hist4[1][i] = base + h0;
            hist4[2][i] = base + h0 + h1;
            hist4[3][i] = base + h0 + h1 + h2;
        }
        __syncthreads();
        // scatter: atomics only within own wave's cursor (near-zero contention)
        for (int i = 0; i < PCH / 256; ++i) {
            int e = e0 + i * 256 + t;
            if (e < EEDGES) {
                int d = dst[e];
                int b = d >> 7;
                int off = atomicAdd(&hist4[w][b], 1);
                if (off < CAP)
                    edgeBin[(size_t)b * CAP + off] = ((unsigned)(d & 127) << 17) | (unsigned)src[e];
            }
        }
    } else {
        // ---- pack path: 8 elems/thread ----
        int tt = (blockIdx.x - NPB) * 256 + t;
        int base = tt * 8;
        const float* srcp;
        unsigned short* dstp;
        int off;
        if (base < NNODES * FIN) {
            srcp = x; off = base; dstp = xb + base;
        } else {
            int w2 = base - NNODES * FIN;
            if (w2 >= 36864) return;
            dstp = wb + w2;
            if (w2 < 16384)      { srcp = Wl1; off = w2; }
            else if (w2 < 32768) { srcp = Wr1; off = w2 - 16384; }
            else if (w2 < 34816) { srcp = Wl2; off = w2 - 32768; }
            else                 { srcp = Wr2; off = w2 - 34816; }
        }
        float4 f0 = *reinterpret_cast<const float4*>(srcp + off);
        float4 f1 = *reinterpret_cast<const float4*>(srcp + off + 4);
        uint4 r;
        r.x = packbf(f0.x, f0.y);
        r.y = packbf(f0.z, f0.w);
        r.z = packbf(f1.x, f1.y);
        r.w = packbf(f1.z, f1.w);
        *reinterpret_cast<uint4*>(dstp) = r;
    }
}

// ---------------- K2: fused bucket: binOff reduction + LDS histogram/scan + scatter --------
__global__ void bucket_fused_kernel(const unsigned int* __restrict__ edgeBin,
                                    const int* __restrict__ binFill,
                                    int* __restrict__ srcSorted,
                                    int* __restrict__ rowstart) {
    __shared__ unsigned eb[CAP];
    __shared__ int cnt[128];
    __shared__ int sc[128];
    __shared__ int wp[128];
    __shared__ int wsum[4];
    int b = blockIdx.x;
    int t = threadIdx.x;

    int contrib = 0;
    if (t < NBIN && t < b) contrib += binFill[t];
    int t2 = t + 256;
    if (t2 < NBIN && t2 < b) contrib += binFill[t2];
    for (int off = 32; off; off >>= 1) contrib += __shfl_down(contrib, off, 64);
    if ((t & 63) == 0) wsum[t >> 6] = contrib;
    if (t < 128) cnt[t] = 0;
    __syncthreads();
    int binOffB = wsum[0] + wsum[1] + wsum[2] + wsum[3];

    int n = min(binFill[b], CAP);
    for (int k = t; k < n; k += 256) {
        unsigned c = edgeBin[(size_t)b * CAP + k];
        eb[k] = c;
        atomicAdd(&cnt[c >> 17], 1);
    }
    __syncthreads();

    if (t < 128) sc[t] = cnt[t];
    __syncthreads();
    for (int off = 1; off < 128; off <<= 1) {
        int v = (t < 128 && t >= off) ? sc[t - off] : 0;
        __syncthreads();
        if (t < 128) sc[t] += v;
        __syncthreads();
    }
    if (t < 128) {
        int node = b * 128 + t;
        int rs = binOffB + sc[t] - cnt[t];
        wp[t] = rs;
        if (node < NNODES) rowstart[node] = rs;
    }
    if (b == 0 && t == 128) rowstart[NNODES] = EEDGES;
    __syncthreads();

    for (int k = t; k < n; k += 256) {
        unsigned c = eb[k];
        int p = atomicAdd(&wp[c >> 17], 1);
        srcSorted[p] = (int)(c & 0x1FFFF);
    }
}

// ---------------- K3: gather 128 features (2 edges/instr via half-wave split) ----------------
__global__ void gather_bf16(const unsigned short* __restrict__ feat,
                            const int* __restrict__ rowstart,
                            const int* __restrict__ srcSorted,
                            unsigned short* __restrict__ aggout) {
    int tid = threadIdx.x;
    int i = blockIdx.x * 4 + (tid >> 6);
    int lane = tid & 63;
    int half = lane >> 5;     // which edge of the pair
    int j = lane & 31;        // uint2 slot within the 256B row
    const uint2* fp = (const uint2*)feat;
    int k0 = rowstart[i], k1 = rowstart[i + 1];
    float a0 = 0.0f, a1 = 0.0f, a2 = 0.0f, a3 = 0.0f;
    int k = k0;
    for (; k + 8 <= k1; k += 8) {
        int sA = srcSorted[k + half];
        int sB = srcSorted[k + 2 + half];
        int sC = srcSorted[k + 4 + half];
        int sD = srcSorted[k + 6 + half];
        uint2 uA = fp[(size_t)sA * 32 + j];
        uint2 uB = fp[(size_t)sB * 32 + j];
        uint2 uC = fp[(size_t)sC * 32 + j];
        uint2 uD = fp[(size_t)sD * 32 + j];
        a0 += lo16(uA.x) + lo16(uB.x) + lo16(uC.x) + lo16(uD.x);
        a1 += hi16(uA.x) + hi16(uB.x) + hi16(uC.x) + hi16(uD.x);
        a2 += lo16(uA.y) + lo16(uB.y) + lo16(uC.y) + lo16(uD.y);
        a3 += hi16(uA.y) + hi16(uB.y) + hi16(uC.y) + hi16(uD.y);
    }
    for (; k + 2 <= k1; k += 2) {
        int s = srcSorted[k + half];
        uint2 u = fp[(size_t)s * 32 + j];
        a0 += lo16(u.x); a1 += hi16(u.x); a2 += lo16(u.y); a3 += hi16(u.y);
    }
    if (k < k1 && half == 0) {
        int s = srcSorted[k];
        uint2 u = fp[(size_t)s * 32 + j];
        a0 += lo16(u.x); a1 += hi16(u.x); a2 += lo16(u.y); a3 += hi16(u.y);
    }
    a0 += __shfl_xor(a0, 32); a1 += __shfl_xor(a1, 32);
    a2 += __shfl_xor(a2, 32); a3 += __shfl_xor(a3, 32);
    if (half == 0) {
        float inv = 1.0f / (float)max(k1 - k0, 1);
        uint2 r;
        r.x = packbf(a0 * inv, a1 * inv);
        r.y = packbf(a2 * inv, a3 * inv);
        ((uint2*)aggout)[(size_t)i * 32 + j] = r;
    }
}

// ---------------- K4: lin1 persistent-weight MFMA + fused BN partials ----------------
__global__ void __launch_bounds__(256, 2)
lin1_persist(const unsigned short* __restrict__ aggb,
             const unsigned short* __restrict__ xb,
             const unsigned short* __restrict__ wl,
             const unsigned short* __restrict__ wr,
             const float* __restrict__ bias,
             unsigned short* __restrict__ hb,
             float* __restrict__ bnsum, float* __restrict__ bnsq) {
    __shared__ float bps[128];
    __shared__ float bpq[128];
    int tid = threadIdx.x;
    if (tid < 128) { bps[tid] = 0.0f; bpq[tid] = 0.0f; }
    __syncthreads();
    int wave = tid >> 6;
    int lane = tid & 63;
    int c = wave & 1;
    int rsub = wave >> 1;
    int lrow = lane & 15;
    int kg = lane >> 4;

    bf16x8 wlF[4][4], wrF[4][4];
    #pragma unroll
    for (int nf = 0; nf < 4; ++nf) {
        #pragma unroll
        for (int ks = 0; ks < 4; ++ks) {
            wlF[nf][ks] = *(const bf16x8*)(wl + (size_t)(c * 64 + nf * 16 + lrow) * 128 + ks * 32 + kg * 8);
            wrF[nf][ks] = *(const bf16x8*)(wr + (size_t)(c * 64 + nf * 16 + lrow) * 128 + ks * 32 + kg * 8);
        }
    }
    float bias_v[4];
    #pragma unroll
    for (int nf = 0; nf < 4; ++nf) bias_v[nf] = bias[c * 64 + nf * 16 + lrow];

    for (int tIt = blockIdx.x; tIt < NTILES; tIt += gridDim.x) {
        int rowA = tIt * 32 + rsub * 16 + lrow;
        int arow = min(rowA, NNODES - 1);
        bf16x8 aA[4], aX[4];
        #pragma unroll
        for (int ks = 0; ks < 4; ++ks) {
            aA[ks] = *(const bf16x8*)(aggb + (size_t)arow * 128 + ks * 32 + kg * 8);
            aX[ks] = *(const bf16x8*)(xb + (size_t)arow * 128 + ks * 32 + kg * 8);
        }
        f32x4 acc[4] = {};
        #pragma unroll
        for (int ks = 0; ks < 4; ++ks) {
            #pragma unroll
            for (int nf = 0; nf < 4; ++nf) {
                acc[nf] = __builtin_amdgcn_mfma_f32_16x16x32_bf16(aA[ks], wlF[nf][ks], acc[nf], 0, 0, 0);
                acc[nf] = __builtin_amdgcn_mfma_f32_16x16x32_bf16(aX[ks], wrF[nf][ks], acc[nf], 0, 0, 0);
            }
        }
        #pragma unroll
        for (int nf = 0; nf < 4; ++nf) {
            float s = 0.0f, q = 0.0f;
            #pragma unroll
            for (int rr = 0; rr < 4; ++rr) {
                int row = tIt * 32 + rsub * 16 + kg * 4 + rr;
                if (row < NNODES) {
                    unsigned short hv = tobf16(acc[nf][rr] + bias_v[nf]);
                    float vr = frombf16(hv);
                    hb[(size_t)row * 128 + c * 64 + nf * 16 + lrow] = hv;
                    s += vr; q += vr * vr;
                }
            }
            s += __shfl_xor(s, 16); s += __shfl_xor(s, 32);
            q += __shfl_xor(q, 16); q += __shfl_xor(q, 32);
            if (lane < 16) {
                atomicAdd(&bps[c * 64 + nf * 16 + lane], s);
                atomicAdd(&bpq[c * 64 + nf * 16 + lane], q);
            }
        }
    }
    __syncthreads();
    if (tid < 128) {
        atomicAdd(&bnsum[tid], bps[tid]);
        atomicAdd(&bnsq[tid], bpq[tid]);
    }
}

// ---------------- K5: fused BN apply + PReLU + residual + y2 = h'@Wl2^T ----------------
__global__ void bn_lin2a_kernel(unsigned short* __restrict__ hb,
                                const unsigned short* __restrict__ xb,
                                const float* __restrict__ gamma, const float* __restrict__ beta,
                                const float* __restrict__ aptr,
                                const float* __restrict__ bnsum, const float* __restrict__ bnsq,
                                const unsigned short* __restrict__ wl,
                                unsigned short* __restrict__ y2) {
    __shared__ float scs[128];
    __shared__ float shs[128];
    int tid = threadIdx.x;
    if (tid < 128) {
        const float invN = 1.0f / (float)NNODES;
        float mean = bnsum[tid] * invN;
        float var = bnsq[tid] * invN - mean * mean;
        float istd = rsqrtf(var + BN_EPS);
        float sc = gamma[tid] * istd;
        scs[tid] = sc;
        shs[tid] = beta[tid] - mean * sc;
    }
    __syncthreads();
    float aP = aptr[0];
    int wave = tid >> 6;
    int lane = tid & 63;
    int row0 = blockIdx.x * 64 + wave * 16;
    int lrow = lane & 15;
    int kg = lane >> 4;
    int rowA = row0 + lrow;
    int arow = min(rowA, NNODES - 1);
    f32x4 acc = {};
    #pragma unroll
    for (int ks = 0; ks < 4; ++ks) {
        bf16x8 hv = *(const bf16x8*)(hb + (size_t)arow * 128 + ks * 32 + kg * 8);
        bf16x8 xv = *(const bf16x8*)(xb + (size_t)arow * 128 + ks * 32 + kg * 8);
        bf16x8 nv;
        #pragma unroll
        for (int e = 0; e < 8; ++e) {
            int f = ks * 32 + kg * 8 + e;
            float v = frombf16((unsigned short)hv[e]) * scs[f] + shs[f];
            v = (v >= 0.0f) ? v : aP * v;
            v += frombf16((unsigned short)xv[e]);
            nv[e] = (short)tobf16(v);
        }
        if (rowA < NNODES)
            *(bf16x8*)(hb + (size_t)arow * 128 + ks * 32 + kg * 8) = nv;
        bf16x8 b = *(const bf16x8*)(wl + (size_t)lrow * 128 + ks * 32 + kg * 8);
        acc = __builtin_amdgcn_mfma_f32_16x16x32_bf16(nv, b, acc, 0, 0, 0);
    }
    #pragma unroll
    for (int r = 0; r < 4; ++r) {
        int row = row0 + kg * 4 + r;
        if (row < NNODES)
            y2[(size_t)row * 16 + lrow] = tobf16(acc[r]);
    }
}

// ---------------- K6: gather 16 features (standalone, 50K waves) ----------------
__global__ void gather16_kernel(const unsigned short* __restrict__ y2,
                                const int* __restrict__ rowstart,
                                const int* __restrict__ srcSorted,
                                unsigned short* __restrict__ agg2) {
    int tid = threadIdx.x;
    int i = blockIdx.x * 4 + (tid >> 6);
    int lane = tid & 63;
    int e = lane >> 3;
    int j = lane & 7;
    const unsigned int* yp = (const unsigned int*)y2;
    int k0 = rowstart[i], k1 = rowstart[i + 1];
    float a0 = 0.0f, a1 = 0.0f;
    for (int k = k0; k < k1; k += 8) {
        int kk = k + e;
        if (kk < k1) {
            unsigned u = yp[(size_t)srcSorted[kk] * 8 + j];
            a0 += lo16(u);
            a1 += hi16(u);
        }
    }
    a0 += __shfl_xor(a0, 8);  a1 += __shfl_xor(a1, 8);
    a0 += __shfl_xor(a0, 16); a1 += __shfl_xor(a1, 16);
    a0 += __shfl_xor(a0, 32); a1 += __shfl_xor(a1, 32);
    if (e == 0) {
        float inv = 1.0f / (float)max(k1 - k0, 1);
        ((unsigned int*)agg2)[(size_t)i * 8 + j] = packbf(a0 * inv, a1 * inv);
    }
}

// ---------------- K7: out = agg2 + hb@Wr2^T + bl2 -> log_softmax ----------------
__global__ void lin2b_kernel(const unsigned short* __restrict__ agg2,
                             const unsigned short* __restrict__ hb,
                             const unsigned short* __restrict__ wr,
                             const float* __restrict__ bias,
                             float* __restrict__ out) {
    int wave = threadIdx.x >> 6;
    int lane = threadIdx.x & 63;
    int row0 = blockIdx.x * 64 + wave * 16;
    int lrow = lane & 15;
    int kg = lane >> 4;
    int arow = min(row0 + lrow, NNODES - 1);
    f32x4 acc = {};
    #pragma unroll
    for (int ks = 0; ks < 4; ++ks) {
        bf16x8 a = *(const bf16x8*)(hb + (size_t)arow * 128 + ks * 32 + kg * 8);
        bf16x8 b = *(const bf16x8*)(wr + (size_t)lrow * 128 + ks * 32 + kg * 8);
        acc = __builtin_amdgcn_mfma_f32_16x16x32_bf16(a, b, acc, 0, 0, 0);
    }
    float bl = bias[lrow];
    #pragma unroll
    for (int r = 0; r < 4; ++r) {
        int row = row0 + kg * 4 + r;
        int rowc = min(row, NNODES - 1);
        float v = acc[r] + bl + frombf16(agg2[(size_t)rowc * 16 + lrow]);
        float m = v;
        for (int s = 1; s < 16; s <<= 1) m = fmaxf(m, __shfl_xor(m, s, 16));
        float ex = expf(v - m);
        float se = ex;
        for (int s = 1; s < 16; s <<= 1) se += __shfl_xor(se, s, 16);
        if (row < NNODES)
            out[(size_t)row * FOUT + lrow] = v - m - logf(se);
    }
}

extern "C" void kernel_launch(void* const* d_in, const int* in_sizes, int n_in,
                              void* d_out, int out_size, void* d_ws, size_t ws_size,
                              hipStream_t stream) {
    const float* x    = (const float*)d_in[0];
    const int*   ei   = (const int*)d_in[1];
    const int*   src  = ei;
    const int*   dst  = ei + EEDGES;
    const float* Wl1  = (const float*)d_in[2];
    const float* bl1  = (const float*)d_in[3];
    const float* Wr1  = (const float*)d_in[4];
    const float* Wl2  = (const float*)d_in[5];
    const float* bl2  = (const float*)d_in[6];
    const float* Wr2  = (const float*)d_in[7];
    const float* gamma= (const float*)d_in[8];
    const float* beta = (const float*)d_in[9];
    const float* a    = (const float*)d_in[10];
    float* out = (float*)d_out;

    char* W = (char*)d_ws;
    unsigned short* xb    = (unsigned short*)(W + 0);           // 12,800,000 B
    unsigned short* hb    = (unsigned short*)(W + 12800000);    // 12,800,000 B
    unsigned int*  edgeBin= (unsigned int*)(W + 25600000);      // 6,406,144 B (dead after K2)
    unsigned short* aggb  = (unsigned short*)(W + 25600000);    // 12,800,000 B (overlays edgeBin)
    unsigned short* y2b   = (unsigned short*)(W + 25600000);    // 1,600,000 B (overlays aggb)
    unsigned short* agg2b = (unsigned short*)(W + 27200000);    // 1,600,000 B
    unsigned short* wb    = (unsigned short*)(W + 38400000);    // 73,728 B
    int* binFill  = (int*)(W + 38473728);                       // 1,564 B
    float* bnsum  = (float*)(W + 38475292);                     // 512 B
    float* bnsq   = (float*)(W + 38475804);                     // 512 B
    int* rowstart = (int*)(W + 38678072);                       // 200,004 B
    int* srcSorted= (int*)(W + 38878076);                       // 3,200,000 B

    unsigned short* wl1b = wb;
    unsigned short* wr1b = wb + 16384;
    unsigned short* wl2b = wb + 32768;
    unsigned short* wr2b = wb + 34816;

    zero_kernel<<<1, 256, 0, stream>>>(binFill);

    part_pack_kernel<<<NPB + PACKBLKS, 256, 0, stream>>>(src, dst, binFill, edgeBin,
                                                         x, Wl1, Wr1, Wl2, Wr2, xb, wb);
    bucket_fused_kernel<<<NBIN, 256, 0, stream>>>(edgeBin, binFill, srcSorted, rowstart);

    // layer 1
    gather_bf16<<<NNODES / 4, 256, 0, stream>>>(xb, rowstart, srcSorted, aggb);
    lin1_persist<<<512, 256, 0, stream>>>(aggb, xb, wl1b, wr1b, bl1, hb, bnsum, bnsq);

    // fused BN/PReLU/residual + lin2a
    bn_lin2a_kernel<<<782, 256, 0, stream>>>(hb, xb, gamma, beta, a, bnsum, bnsq, wl2b, y2b);

    // layer 2 aggregate + final
    gather16_kernel<<<NNODES / 4, 256, 0, stream>>>(y2b, rowstart, srcSorted, agg2b);
    lin2b_kernel<<<782, 256, 0, stream>>>(agg2b, hb, wr2b, bl2, out);
}